// Round 3
// baseline (1668.245 us; speedup 1.0000x reference)
//
#include <hip/hip_runtime.h>
#include <hip/hip_bf16.h>

// Problem constants
#define NT 8192        // tokens = B*S
#define DIM_ 1024
#define HID_ 4096
#define NE 8

// GEMM tile config
#define TM 128
#define TN 128
#define BK 32

typedef unsigned short u16;
typedef __attribute__((ext_vector_type(8))) short bf16x8;
typedef __attribute__((ext_vector_type(4))) float f32x4;

__device__ __forceinline__ u16 f2b(float f) {
  unsigned u = __float_as_uint(f);
  return (u16)((u + 0x7FFFu + ((u >> 16) & 1u)) >> 16);  // RNE bf16
}

// async global->LDS, 16B per lane. LDS dest must be wave-uniform base + lane*16.
typedef __attribute__((address_space(1))) const unsigned int ga_u32;
typedef __attribute__((address_space(3))) unsigned int lds_u32;
__device__ __forceinline__ void gl16(const u16* g, u16* l) {
  __builtin_amdgcn_global_load_lds((ga_u32*)g, (lds_u32*)l, 16, 0, 0);
}

// ---------------- x fp32 -> bf16 ----------------
__global__ __launch_bounds__(256) void cvt_x_kernel(const float* __restrict__ x,
                                                    u16* __restrict__ xb) {
  int i = (blockIdx.x * 256 + threadIdx.x) * 4;
  f32x4 v = *(const f32x4*)(x + i);
  ushort4 o;
  o.x = f2b(v.x); o.y = f2b(v.y); o.z = f2b(v.z); o.w = f2b(v.w);
  *(ushort4*)(xb + i) = o;
}

// ---------------- weight fp32 [e][K][N] -> bf16 [e][N][K] ----------------
// grid (N/64, K/64, E), 256 threads, 64x64 tile
__global__ __launch_bounds__(256) void tpose_kernel(const float* __restrict__ src,
                                                    u16* __restrict__ dst, int K, int N) {
  int e = blockIdx.z;
  int n0 = blockIdx.x * 64, k0 = blockIdx.y * 64;
  __shared__ u16 t[64][72];
  int tid = threadIdx.x;
  int kl = tid >> 4, cl = (tid & 15) * 4;
  const float* s = src + ((size_t)e * K + k0) * N + n0;
#pragma unroll
  for (int i = 0; i < 4; i++) {
    f32x4 v = *(const f32x4*)(s + (size_t)(kl + i * 16) * N + cl);
    ushort4 o; o.x = f2b(v.x); o.y = f2b(v.y); o.z = f2b(v.z); o.w = f2b(v.w);
    *(ushort4*)&t[kl + i * 16][cl] = o;
  }
  __syncthreads();
  int nl = tid >> 2, kc = (tid & 3) * 16;
  u16* d = dst + ((size_t)e * N + n0 + nl) * K + k0 + kc;
  unsigned p[8];
#pragma unroll
  for (int j = 0; j < 8; j++)
    p[j] = (unsigned)t[kc + 2 * j][nl] | ((unsigned)t[kc + 2 * j + 1][nl] << 16);
  *(uint4*)d = make_uint4(p[0], p[1], p[2], p[3]);
  *(uint4*)(d + 8) = make_uint4(p[4], p[5], p[6], p[7]);
}

// ---------------- router ----------------
__global__ __launch_bounds__(256) void router_kernel(
    const float* __restrict__ x, const float* __restrict__ gw,
    int* __restrict__ elist, float* __restrict__ pw,
    int* __restrict__ count, float* __restrict__ usage) {
  __shared__ float us[NE];
  int tid = threadIdx.x;
  if (tid < NE) us[tid] = 0.f;
  __syncthreads();
  int wave = tid >> 6, lane = tid & 63;
  int base = (blockIdx.x * 4 + wave) * 16;
  for (int i = 0; i < 16; ++i) {
    int t = base + i;
    float acc[NE];
#pragma unroll
    for (int e = 0; e < NE; e++) acc[e] = 0.f;
    for (int d = lane; d < DIM_; d += 64) {
      float xv = x[t * DIM_ + d];
      const float* g = gw + d * NE;
#pragma unroll
      for (int e = 0; e < NE; e++) acc[e] += xv * g[e];
    }
#pragma unroll
    for (int off = 32; off; off >>= 1) {
#pragma unroll
      for (int e = 0; e < NE; e++) acc[e] += __shfl_xor(acc[e], off);
    }
    if (lane == 0) {
      float m = acc[0];
#pragma unroll
      for (int e = 1; e < NE; e++) m = fmaxf(m, acc[e]);
      float Z = 0.f, ex[NE];
#pragma unroll
      for (int e = 0; e < NE; e++) { ex[e] = __expf(acc[e] - m); Z += ex[e]; }
#pragma unroll
      for (int e = 0; e < NE; e++) atomicAdd(&us[e], ex[e] / Z);
      int i0 = 0;
#pragma unroll
      for (int e = 1; e < NE; e++) if (acc[e] > acc[i0]) i0 = e;
      int i1 = -1;
#pragma unroll
      for (int e = 0; e < NE; e++) {
        if (e == i0) continue;
        if (i1 < 0 || acc[e] > acc[i1]) i1 = e;
      }
      float w0 = 1.f / (1.f + __expf(acc[i1] - acc[i0]));
      float w1 = 1.f - w0;
      int p0 = atomicAdd(&count[i0], 1);
      elist[i0 * NT + p0] = 2 * t;
      pw[2 * t] = w0;
      int p1 = atomicAdd(&count[i1], 1);
      elist[i1 * NT + p1] = 2 * t + 1;
      pw[2 * t + 1] = w1;
    }
  }
  __syncthreads();
  if (tid < NE) atomicAdd(&usage[tid], us[tid]);
}

// ---------------- aux loss ----------------
__global__ void aux_kernel(const float* __restrict__ usage, float* __restrict__ out_aux) {
  if (threadIdx.x == 0) {
    float s = 0.f;
    for (int e = 0; e < NE; e++) { float u = usage[e] / (float)NT; s += u * u; }
    *out_aux = (float)NE * s;
  }
}

// ---------------- stage 1: H = silu(X@W1) * (X@W3) * combine_w  (bf16 out) ----------------
// wt1/wt3: bf16 [e][n=HID][k=DIM] (k-contiguous)
// grid 16384 1-D: expert = wgid&7 (one expert per XCD), tile fastest within expert.
// 3-buffer LDS, depth-2 prefetch, counted vmcnt (never 0 in steady state), raw s_barrier.
// Per step i: vmcnt(6) [own block-i loads landed] -> s_barrier [collective ready +
// all waves past compute(i-1)] -> stage block i+2 into buf[(i+2)%3] (last read step i-1)
// -> compute buf[i].
__global__ __launch_bounds__(256) void stage1_kernel(
    const u16* __restrict__ xb, const u16* __restrict__ wt1, const u16* __restrict__ wt3,
    const int* __restrict__ elist, const int* __restrict__ count,
    const float* __restrict__ pw, u16* __restrict__ hbuf) {
  int wgid = blockIdx.x;
  int e = wgid & 7;                // XCD-local expert
  int k = wgid >> 3;
  int tile = k & 63;               // fastest: same-panel readers adjacent in time
  int n0 = (k >> 6) * TN;          // 0..31
  int cnt = count[e];
  if (tile * TM >= cnt) return;

  __shared__ u16 As[3][TM * BK];    // 3 x 8 KB
  __shared__ u16 B1s[3][TN * BK];   // 3 x 8 KB
  __shared__ u16 B3s[3][TN * BK];   // 3 x 8 KB
  __shared__ int slots[TM];
  __shared__ float pws[TM];

  int tid = threadIdx.x;
  if (tid < TM) {
    int r = tile * TM + tid;
    int s = (r < cnt) ? elist[e * NT + r] : -1;
    slots[tid] = s;
    pws[tid] = (s >= 0) ? pw[s] : 0.f;
  }
  __syncthreads();

  // staging geometry: thread covers (row = tid>>2, 16B chunk = tid&3) and row+64
  int lrow = tid >> 2;
  int lcol = (tid & 3) * 8;
  int sl0 = slots[lrow], sl1 = slots[lrow + 64];
  const u16* gA0 = xb + (size_t)((sl0 >= 0 ? sl0 : 0) >> 1) * DIM_ + lcol;
  const u16* gA1 = xb + (size_t)((sl1 >= 0 ? sl1 : 0) >> 1) * DIM_ + lcol;
  const u16* gB1a = wt1 + ((size_t)e * HID_ + n0 + lrow) * DIM_ + lcol;
  const u16* gB1b = gB1a + (size_t)64 * DIM_;
  const u16* gB3a = wt3 + ((size_t)e * HID_ + n0 + lrow) * DIM_ + lcol;
  const u16* gB3b = gB3a + (size_t)64 * DIM_;

  int wv = tid >> 6, lane = tid & 63;
  int wm = (wv & 1) * 64, wn = (wv >> 1) * 64;
  int fr = lane & 15, fk = (lane >> 4) * 8;

  f32x4 acc1[4][4], acc3[4][4];
  f32x4 zero = {0.f, 0.f, 0.f, 0.f};
#pragma unroll
  for (int i = 0; i < 4; i++)
#pragma unroll
    for (int j = 0; j < 4; j++) { acc1[i][j] = zero; acc3[i][j] = zero; }

#define S1_STAGE(B, K0)                          \
  gl16(gA0 + (K0), &As[B][tid * 8]);             \
  gl16(gA1 + (K0), &As[B][2048 + tid * 8]);      \
  gl16(gB1a + (K0), &B1s[B][tid * 8]);           \
  gl16(gB1b + (K0), &B1s[B][2048 + tid * 8]);    \
  gl16(gB3a + (K0), &B3s[B][tid * 8]);           \
  gl16(gB3b + (K0), &B3s[B][2048 + tid * 8]);

#define S1_COMPUTE(B)                                                          \
  { bf16x8 afr[4], b1fr[4], b3fr[4];                                           \
    _Pragma("unroll") for (int i = 0; i < 4; i++)                              \
      afr[i] = *(const bf16x8*)&As[B][(wm + i * 16 + fr) * BK + fk];           \
    _Pragma("unroll") for (int j = 0; j < 4; j++) {                            \
      b1fr[j] = *(const bf16x8*)&B1s[B][(wn + j * 16 + fr) * BK + fk];         \
      b3fr[j] = *(const bf16x8*)&B3s[B][(wn + j * 16 + fr) * BK + fk];         \
    }                                                                          \
    _Pragma("unroll") for (int i = 0; i < 4; i++)                              \
      _Pragma("unroll") for (int j = 0; j < 4; j++) {                          \
        acc1[i][j] = __builtin_amdgcn_mfma_f32_16x16x32_bf16(afr[i], b1fr[j], acc1[i][j], 0, 0, 0); \
        acc3[i][j] = __builtin_amdgcn_mfma_f32_16x16x32_bf16(afr[i], b3fr[j], acc3[i][j], 0, 0, 0); \
      } }

  S1_STAGE(0, 0);
  S1_STAGE(1, BK);
  int b0 = 0;
  for (int k0 = 0; k0 < DIM_; k0 += BK) {
    if (k0 + BK < DIM_) {
      asm volatile("s_waitcnt vmcnt(6)" ::: "memory");   // block-i landed, i+1 in flight
    } else {
      asm volatile("s_waitcnt vmcnt(0)" ::: "memory");   // last step: drain
    }
    __builtin_amdgcn_s_barrier();
    __builtin_amdgcn_sched_barrier(0);
    if (k0 + 2 * BK < DIM_) {
      int b2 = b0 + 2; if (b2 >= 3) b2 -= 3;
      S1_STAGE(b2, k0 + 2 * BK);
    }
    S1_COMPUTE(b0);
    if (++b0 == 3) b0 = 0;
  }

#pragma unroll
  for (int i = 0; i < 4; i++) {
#pragma unroll
    for (int r4 = 0; r4 < 4; r4++) {
      int row = wm + i * 16 + (lane >> 4) * 4 + r4;
      int s = slots[row];
      if (s < 0) continue;
      float w = pws[row];
      u16* dst = hbuf + (size_t)s * HID_ + n0 + wn + (lane & 15);
#pragma unroll
      for (int j = 0; j < 4; j++) {
        float p1 = acc1[i][j][r4];
        float p3 = acc3[i][j][r4];
        float h = (p1 / (1.f + __expf(-p1))) * p3 * w;
        dst[j * 16] = f2b(h);
      }
    }
  }
}

// ---------------- stage 2: Y = H @ W2, scatter atomicAdd into out ----------------
// wt2: bf16 [e][n=DIM][k=HID]
// grid 4096 1-D: expert = wgid&7, tile fastest. Same 3-buffer counted-vmcnt pipeline.
__global__ __launch_bounds__(256) void stage2_kernel(
    const u16* __restrict__ hbuf, const u16* __restrict__ wt2,
    const int* __restrict__ elist, const int* __restrict__ count,
    float* __restrict__ out) {
  int wgid = blockIdx.x;
  int e = wgid & 7;
  int k = wgid >> 3;
  int tile = k & 63;
  int n0 = (k >> 6) * TN;          // 0..7
  int cnt = count[e];
  if (tile * TM >= cnt) return;

  __shared__ u16 As[3][TM * BK];   // 3 x 8 KB
  __shared__ u16 Bs[3][TN * BK];   // 3 x 8 KB
  __shared__ int slots[TM];

  int tid = threadIdx.x;
  if (tid < TM) {
    int r = tile * TM + tid;
    slots[tid] = (r < cnt) ? elist[e * NT + r] : -1;
  }
  __syncthreads();

  int lrow = tid >> 2;
  int lcol = (tid & 3) * 8;
  int sl0 = slots[lrow], sl1 = slots[lrow + 64];
  const u16* gA0 = hbuf + (size_t)(sl0 >= 0 ? sl0 : 0) * HID_ + lcol;
  const u16* gA1 = hbuf + (size_t)(sl1 >= 0 ? sl1 : 0) * HID_ + lcol;
  const u16* gBa = wt2 + ((size_t)e * DIM_ + n0 + lrow) * HID_ + lcol;
  const u16* gBb = gBa + (size_t)64 * HID_;

  int wv = tid >> 6, lane = tid & 63;
  int wm = (wv & 1) * 64, wn = (wv >> 1) * 64;
  int fr = lane & 15, fk = (lane >> 4) * 8;

  f32x4 acc[4][4];
  f32x4 zero = {0.f, 0.f, 0.f, 0.f};
#pragma unroll
  for (int i = 0; i < 4; i++)
#pragma unroll
    for (int j = 0; j < 4; j++) acc[i][j] = zero;

#define S2_STAGE(B, K0)                          \
  gl16(gA0 + (K0), &As[B][tid * 8]);             \
  gl16(gA1 + (K0), &As[B][2048 + tid * 8]);      \
  gl16(gBa + (K0), &Bs[B][tid * 8]);             \
  gl16(gBb + (K0), &Bs[B][2048 + tid * 8]);

#define S2_COMPUTE(B)                                                          \
  { bf16x8 afr[4], bfr[4];                                                     \
    _Pragma("unroll") for (int i = 0; i < 4; i++)                              \
      afr[i] = *(const bf16x8*)&As[B][(wm + i * 16 + fr) * BK + fk];           \
    _Pragma("unroll") for (int j = 0; j < 4; j++)                              \
      bfr[j] = *(const bf16x8*)&Bs[B][(wn + j * 16 + fr) * BK + fk];           \
    _Pragma("unroll") for (int i = 0; i < 4; i++)                              \
      _Pragma("unroll") for (int j = 0; j < 4; j++)                            \
        acc[i][j] = __builtin_amdgcn_mfma_f32_16x16x32_bf16(afr[i], bfr[j], acc[i][j], 0, 0, 0); }

  S2_STAGE(0, 0);
  S2_STAGE(1, BK);
  int b0 = 0;
  for (int k0 = 0; k0 < HID_; k0 += BK) {
    if (k0 + BK < HID_) {
      asm volatile("s_waitcnt vmcnt(4)" ::: "memory");
    } else {
      asm volatile("s_waitcnt vmcnt(0)" ::: "memory");
    }
    __builtin_amdgcn_s_barrier();
    __builtin_amdgcn_sched_barrier(0);
    if (k0 + 2 * BK < HID_) {
      int b2 = b0 + 2; if (b2 >= 3) b2 -= 3;
      S2_STAGE(b2, k0 + 2 * BK);
    }
    S2_COMPUTE(b0);
    if (++b0 == 3) b0 = 0;
  }

#pragma unroll
  for (int i = 0; i < 4; i++) {
#pragma unroll
    for (int r4 = 0; r4 < 4; r4++) {
      int row = wm + i * 16 + (lane >> 4) * 4 + r4;
      int s = slots[row];
      if (s < 0) continue;
      int tk = s >> 1;
      float* dst = out + (size_t)tk * DIM_ + n0 + wn + (lane & 15);
#pragma unroll
      for (int j = 0; j < 4; j++) atomicAdd(&dst[j * 16], acc[i][j][r4]);
    }
  }
}

extern "C" void kernel_launch(void* const* d_in, const int* in_sizes, int n_in,
                              void* d_out, int out_size, void* d_ws, size_t ws_size,
                              hipStream_t stream) {
  const float* x = (const float*)d_in[0];
  const float* gw = (const float*)d_in[1];
  const float* w1 = (const float*)d_in[2];
  const float* w2 = (const float*)d_in[3];
  const float* w3 = (const float*)d_in[4];
  float* out = (float*)d_out;

  // workspace layout
  char* ws = (char*)d_ws;
  int* count = (int*)ws;                                    // 8 ints
  float* usage = (float*)(ws + 32);                         // 8 floats
  int* elist = (int*)(ws + 256);                            // NE*NT ints = 262144 B
  float* pw = (float*)(ws + 256 + 262144);                  // 2*NT floats = 65536 B
  u16* xb = (u16*)(ws + 327936);                            // NT*DIM bf16 = 16 MB
  u16* hbuf = (u16*)(ws + 327936 + 16777216);               // 2*NT*HID bf16 = 128 MB
  char* wbase = ws + 327936 + 16777216 + 134217728;         // 128 MB region
  u16* wt1 = (u16*)wbase;                                   // 64 MB
  u16* wt3 = (u16*)(wbase + 67108864);                      // 64 MB
  u16* wt2 = (u16*)wbase;                                   // aliases wt1 (used after stage1)

  hipMemsetAsync(d_out, 0, (size_t)(NT * DIM_ + 1) * sizeof(float), stream);
  hipMemsetAsync(ws, 0, 64, stream);

  cvt_x_kernel<<<(NT * DIM_) / (256 * 4), 256, 0, stream>>>(x, xb);
  router_kernel<<<128, 256, 0, stream>>>(x, gw, elist, pw, count, usage);
  aux_kernel<<<1, 64, 0, stream>>>(usage, out + (size_t)NT * DIM_);
  // transpose+convert w1, w3: fp32 [e][1024][4096] -> bf16 [e][4096][1024]
  tpose_kernel<<<dim3(HID_ / 64, DIM_ / 64, NE), 256, 0, stream>>>(w1, wt1, DIM_, HID_);
  tpose_kernel<<<dim3(HID_ / 64, DIM_ / 64, NE), 256, 0, stream>>>(w3, wt3, DIM_, HID_);
  stage1_kernel<<<dim3(NE * 64 * (HID_ / TN)), 256, 0, stream>>>(xb, wt1, wt3, elist, count, pw, hbuf);
  // transpose+convert w2: fp32 [e][4096][1024] -> bf16 [e][1024][4096] (overwrites wt1 region)
  tpose_kernel<<<dim3(DIM_ / 64, HID_ / 64, NE), 256, 0, stream>>>(w2, wt2, HID_, DIM_);
  stage2_kernel<<<dim3(NE * 64 * (DIM_ / TN)), 256, 0, stream>>>(hbuf, wt2, elist, count, out);
}

// Round 4
// 1312.044 us; speedup vs baseline: 1.2715x; 1.2715x over previous
//
#include <hip/hip_runtime.h>
#include <hip/hip_bf16.h>

// Problem constants
#define NT 8192        // tokens = B*S
#define DIM_ 1024
#define HID_ 4096
#define NE 8

// stage2 tile config (R2-proven structure)
#define TM 128
#define TN 128
#define BK 32

// stage1 tile config (phase-split template)
#define TM1 256
#define TN1 128
#define BK1 64

typedef unsigned short u16;
typedef __attribute__((ext_vector_type(8))) short bf16x8;
typedef __attribute__((ext_vector_type(4))) float f32x4;

__device__ __forceinline__ u16 f2b(float f) {
  unsigned u = __float_as_uint(f);
  return (u16)((u + 0x7FFFu + ((u >> 16) & 1u)) >> 16);  // RNE bf16
}

// async global->LDS, 16B per lane. LDS dest must be wave-uniform base + lane*16.
typedef __attribute__((address_space(1))) const unsigned int ga_u32;
typedef __attribute__((address_space(3))) unsigned int lds_u32;
__device__ __forceinline__ void gl16(const u16* g, u16* l) {
  __builtin_amdgcn_global_load_lds((ga_u32*)g, (lds_u32*)l, 16, 0, 0);
}

// ---------------- x fp32 -> bf16 ----------------
__global__ __launch_bounds__(256) void cvt_x_kernel(const float* __restrict__ x,
                                                    u16* __restrict__ xb) {
  int i = (blockIdx.x * 256 + threadIdx.x) * 4;
  f32x4 v = *(const f32x4*)(x + i);
  ushort4 o;
  o.x = f2b(v.x); o.y = f2b(v.y); o.z = f2b(v.z); o.w = f2b(v.w);
  *(ushort4*)(xb + i) = o;
}

// ---------------- weight fp32 [e][K][N] -> bf16 [e][N][K] ----------------
__global__ __launch_bounds__(256) void tpose_kernel(const float* __restrict__ src,
                                                    u16* __restrict__ dst, int K, int N) {
  int e = blockIdx.z;
  int n0 = blockIdx.x * 64, k0 = blockIdx.y * 64;
  __shared__ u16 t[64][72];
  int tid = threadIdx.x;
  int kl = tid >> 4, cl = (tid & 15) * 4;
  const float* s = src + ((size_t)e * K + k0) * N + n0;
#pragma unroll
  for (int i = 0; i < 4; i++) {
    f32x4 v = *(const f32x4*)(s + (size_t)(kl + i * 16) * N + cl);
    ushort4 o; o.x = f2b(v.x); o.y = f2b(v.y); o.z = f2b(v.z); o.w = f2b(v.w);
    *(ushort4*)&t[kl + i * 16][cl] = o;
  }
  __syncthreads();
  int nl = tid >> 2, kc = (tid & 3) * 16;
  u16* d = dst + ((size_t)e * N + n0 + nl) * K + k0 + kc;
  unsigned p[8];
#pragma unroll
  for (int j = 0; j < 8; j++)
    p[j] = (unsigned)t[kc + 2 * j][nl] | ((unsigned)t[kc + 2 * j + 1][nl] << 16);
  *(uint4*)d = make_uint4(p[0], p[1], p[2], p[3]);
  *(uint4*)(d + 8) = make_uint4(p[4], p[5], p[6], p[7]);
}

// ---------------- router ----------------
__global__ __launch_bounds__(256) void router_kernel(
    const float* __restrict__ x, const float* __restrict__ gw,
    int* __restrict__ elist, float* __restrict__ pw,
    int* __restrict__ count, float* __restrict__ usage) {
  __shared__ float us[NE];
  int tid = threadIdx.x;
  if (tid < NE) us[tid] = 0.f;
  __syncthreads();
  int wave = tid >> 6, lane = tid & 63;
  int base = (blockIdx.x * 4 + wave) * 16;
  for (int i = 0; i < 16; ++i) {
    int t = base + i;
    float acc[NE];
#pragma unroll
    for (int e = 0; e < NE; e++) acc[e] = 0.f;
    for (int d = lane; d < DIM_; d += 64) {
      float xv = x[t * DIM_ + d];
      const float* g = gw + d * NE;
#pragma unroll
      for (int e = 0; e < NE; e++) acc[e] += xv * g[e];
    }
#pragma unroll
    for (int off = 32; off; off >>= 1) {
#pragma unroll
      for (int e = 0; e < NE; e++) acc[e] += __shfl_xor(acc[e], off);
    }
    if (lane == 0) {
      float m = acc[0];
#pragma unroll
      for (int e = 1; e < NE; e++) m = fmaxf(m, acc[e]);
      float Z = 0.f, ex[NE];
#pragma unroll
      for (int e = 0; e < NE; e++) { ex[e] = __expf(acc[e] - m); Z += ex[e]; }
#pragma unroll
      for (int e = 0; e < NE; e++) atomicAdd(&us[e], ex[e] / Z);
      int i0 = 0;
#pragma unroll
      for (int e = 1; e < NE; e++) if (acc[e] > acc[i0]) i0 = e;
      int i1 = -1;
#pragma unroll
      for (int e = 0; e < NE; e++) {
        if (e == i0) continue;
        if (i1 < 0 || acc[e] > acc[i1]) i1 = e;
      }
      float w0 = 1.f / (1.f + __expf(acc[i1] - acc[i0]));
      float w1 = 1.f - w0;
      int p0 = atomicAdd(&count[i0], 1);
      elist[i0 * NT + p0] = 2 * t;
      pw[2 * t] = w0;
      int p1 = atomicAdd(&count[i1], 1);
      elist[i1 * NT + p1] = 2 * t + 1;
      pw[2 * t + 1] = w1;
    }
  }
  __syncthreads();
  if (tid < NE) atomicAdd(&usage[tid], us[tid]);
}

// ---------------- aux loss ----------------
__global__ void aux_kernel(const float* __restrict__ usage, float* __restrict__ out_aux) {
  if (threadIdx.x == 0) {
    float s = 0.f;
    for (int e = 0; e < NE; e++) { float u = usage[e] / (float)NT; s += u * u; }
    *out_aux = (float)NE * s;
  }
}

// ---------------- stage 1: H = silu(X@W1) * (X@W3) * combine_w  (bf16 out) ----------------
// Phase-split template (T2+T3+T4+T5): TM1=256 x TN1=128, BK1=64, 8 waves (512 thr).
// LDS 2dbuf x (A 32K + B1 16K + B3 16K) = 128 KB, 1 block/CU.
// Per K-tile, 4 phases: {ds-read frag subtile; issue 1 half-tile global_load_lds;
//   barrier; lgkmcnt(0)+sched_barrier; setprio(1); 16 MFMA; setprio(0); barrier}.
// Counted vmcnt(2) only at P1/P4 closing (FIFO invariant: A0,A1,B1 land before next
// iter's P1 reads; B3 before next P2 reads). Never drains in steady state.
// T2 swizzle (rule 21: linear LDS dest + inverse-swizzled GLOBAL source + swizzled
// read): 16B-chunk c' = c ^ (row&7) -> ds_read_b128 8-way conflict -> 2-way (free).
__global__ __launch_bounds__(512, 2) void stage1_kernel(
    const u16* __restrict__ xb, const u16* __restrict__ wt1, const u16* __restrict__ wt3,
    const int* __restrict__ elist, const int* __restrict__ count,
    const float* __restrict__ pw, u16* __restrict__ hbuf) {
  int wgid = blockIdx.x;
  int e = wgid & 7;                // XCD-local expert
  int k = wgid >> 3;
  int tile = k & 63;               // 64 slots x 256 rows: safe to cnt=16384
  int n0 = (k >> 6) * TN1;         // 0..31
  int cnt = count[e];
  if (tile * TM1 >= cnt) return;

  __shared__ u16 As[2][TM1 * BK1];   // 2 x 32 KB
  __shared__ u16 B1s[2][TN1 * BK1];  // 2 x 16 KB
  __shared__ u16 B3s[2][TN1 * BK1];  // 2 x 16 KB
  __shared__ int slots[TM1];
  __shared__ float pws[TM1];

  int tid = threadIdx.x;
  if (tid < TM1) {
    int r = tile * TM1 + tid;
    int s = (r < cnt) ? elist[e * NT + r] : -1;
    slots[tid] = s;
    pws[tid] = (s >= 0) ? pw[s] : 0.f;
  }
  __syncthreads();

  // ---- staging geometry: 512 thr x 16B = 8KB/round; half-tile = 2 rounds = 16KB
  int srow = tid >> 3;                              // 0..63 row within round
  int scol = ((tid & 7) ^ (srow & 7)) * 8;          // inverse-swizzled source chunk
  const u16* gA[2][2];                              // [half][round]
#pragma unroll
  for (int h = 0; h < 2; h++)
#pragma unroll
    for (int r = 0; r < 2; r++) {
      int rr = h * 128 + r * 64 + srow;
      int s = slots[rr];
      gA[h][r] = xb + (size_t)((s >= 0 ? s : 0) >> 1) * DIM_ + scol;
    }
  const u16* gB1r0 = wt1 + ((size_t)e * HID_ + n0 + srow) * DIM_ + scol;
  const u16* gB1r1 = gB1r0 + (size_t)64 * DIM_;
  const u16* gB3r0 = wt3 + ((size_t)e * HID_ + n0 + srow) * DIM_ + scol;
  const u16* gB3r1 = gB3r0 + (size_t)64 * DIM_;

#define STG_A(BUF, H, K0)                                   \
  gl16(gA[H][0] + (K0), &As[BUF][(H) * 8192 + tid * 8]);    \
  gl16(gA[H][1] + (K0), &As[BUF][(H) * 8192 + 4096 + tid * 8]);
#define STG_B1(BUF, K0)                                     \
  gl16(gB1r0 + (K0), &B1s[BUF][tid * 8]);                   \
  gl16(gB1r1 + (K0), &B1s[BUF][4096 + tid * 8]);
#define STG_B3(BUF, K0)                                     \
  gl16(gB3r0 + (K0), &B3s[BUF][tid * 8]);                   \
  gl16(gB3r1 + (K0), &B3s[BUF][4096 + tid * 8]);

  // ---- wave / fragment geometry
  int wv = tid >> 6, lane = tid & 63;
  int wm = (wv & 3) * 64;          // 4 M-chunks of 64
  int wn = (wv >> 2) * 64;         // 2 N-chunks of 64
  int fr = lane & 15, q = lane >> 4;
  int sw = fr & 7;
  // swizzled frag offsets (elems); chunk c = ks*4 + q, c' = c ^ (row&7), row&7 = fr&7
  int aof0 = (wm + fr) * 64 + ((q ^ sw)) * 8;
  int aof1 = (wm + fr) * 64 + (((4 + q) ^ sw)) * 8;
  int bof0 = (wn + fr) * 64 + ((q ^ sw)) * 8;
  int bof1 = (wn + fr) * 64 + (((4 + q) ^ sw)) * 8;

  f32x4 acc1[4][4], acc3[4][4];
  f32x4 zero = {0.f, 0.f, 0.f, 0.f};
#pragma unroll
  for (int i = 0; i < 4; i++)
#pragma unroll
    for (int j = 0; j < 4; j++) { acc1[i][j] = zero; acc3[i][j] = zero; }

#define MM16(ACC, AF, BF)                                                      \
  _Pragma("unroll") for (int i = 0; i < 4; i++)                                \
    _Pragma("unroll") for (int j = 0; j < 4; j++)                              \
      ACC[i][j] = __builtin_amdgcn_mfma_f32_16x16x32_bf16(AF[i], BF[j], ACC[i][j], 0, 0, 0);

  // One 4-phase K-tile iteration. CUR/NXT/DO_STAGE/LASTV are literals.
#define S1_ITER(CUR, NXT, KB, DO_STAGE, LASTV)                                 \
  { bf16x8 a0[4], bb[4];                                                       \
    _Pragma("unroll") for (int i = 0; i < 4; i++)                              \
      a0[i] = *(const bf16x8*)&As[CUR][aof0 + i * 1024];                       \
    _Pragma("unroll") for (int j = 0; j < 4; j++)                              \
      bb[j] = *(const bf16x8*)&B1s[CUR][bof0 + j * 1024];                      \
    if (DO_STAGE) { STG_A(NXT, 0, KB); }                                       \
    __builtin_amdgcn_s_barrier();                                              \
    asm volatile("s_waitcnt lgkmcnt(0)" ::: "memory");                         \
    __builtin_amdgcn_sched_barrier(0);                                         \
    __builtin_amdgcn_s_setprio(1); MM16(acc1, a0, bb); __builtin_amdgcn_s_setprio(0); \
    asm volatile("s_waitcnt vmcnt(%0)" :: "i"((LASTV) ? 0 : 2) : "memory");    \
    __builtin_amdgcn_s_barrier();                                              \
    /* P2 */                                                                   \
    _Pragma("unroll") for (int j = 0; j < 4; j++)                              \
      bb[j] = *(const bf16x8*)&B3s[CUR][bof0 + j * 1024];                      \
    if (DO_STAGE) { STG_A(NXT, 1, KB); }                                       \
    __builtin_amdgcn_s_barrier();                                              \
    asm volatile("s_waitcnt lgkmcnt(0)" ::: "memory");                         \
    __builtin_amdgcn_sched_barrier(0);                                         \
    __builtin_amdgcn_s_setprio(1); MM16(acc3, a0, bb); __builtin_amdgcn_s_setprio(0); \
    __builtin_amdgcn_s_barrier();                                              \
    /* P3 */                                                                   \
    _Pragma("unroll") for (int i = 0; i < 4; i++)                              \
      a0[i] = *(const bf16x8*)&As[CUR][aof1 + i * 1024];                       \
    _Pragma("unroll") for (int j = 0; j < 4; j++)                              \
      bb[j] = *(const bf16x8*)&B1s[CUR][bof1 + j * 1024];                      \
    if (DO_STAGE) { STG_B1(NXT, KB); }                                         \
    __builtin_amdgcn_s_barrier();                                              \
    asm volatile("s_waitcnt lgkmcnt(0)" ::: "memory");                         \
    __builtin_amdgcn_sched_barrier(0);                                         \
    __builtin_amdgcn_s_setprio(1); MM16(acc1, a0, bb); __builtin_amdgcn_s_setprio(0); \
    __builtin_amdgcn_s_barrier();                                              \
    /* P4 */                                                                   \
    _Pragma("unroll") for (int j = 0; j < 4; j++)                              \
      bb[j] = *(const bf16x8*)&B3s[CUR][bof1 + j * 1024];                      \
    if (DO_STAGE) { STG_B3(NXT, KB); }                                         \
    __builtin_amdgcn_s_barrier();                                              \
    asm volatile("s_waitcnt lgkmcnt(0)" ::: "memory");                         \
    __builtin_amdgcn_sched_barrier(0);                                         \
    __builtin_amdgcn_s_setprio(1); MM16(acc3, a0, bb); __builtin_amdgcn_s_setprio(0); \
    if (DO_STAGE) { asm volatile("s_waitcnt vmcnt(2)" ::: "memory"); }         \
    __builtin_amdgcn_s_barrier(); }

  // prologue: fully stage buf0 (K-tile 0), drain once, collective ready
  STG_A(0, 0, 0); STG_A(0, 1, 0); STG_B1(0, 0); STG_B3(0, 0);
  asm volatile("s_waitcnt vmcnt(0)" ::: "memory");
  __builtin_amdgcn_s_barrier();

  // 16 K-tiles: 7 unrolled pairs + t=14 (stages last tile) + t=15 (no stage)
  for (int p = 0; p < 7; ++p) {
    int kb1 = (2 * p + 1) * BK1;
    int kb2 = (2 * p + 2) * BK1;
    S1_ITER(0, 1, kb1, 1, 0);
    S1_ITER(1, 0, kb2, 1, 0);
  }
  S1_ITER(0, 1, 15 * BK1, 1, 0);
  S1_ITER(1, 0, 0, 0, 1);

  // ---- epilogue: silu(p1)*p3*w -> bf16 scatter into hbuf
#pragma unroll
  for (int i = 0; i < 4; i++) {
#pragma unroll
    for (int r4 = 0; r4 < 4; r4++) {
      int row = wm + i * 16 + (lane >> 4) * 4 + r4;
      int s = slots[row];
      if (s < 0) continue;
      float w = pws[row];
      u16* dst = hbuf + (size_t)s * HID_ + n0 + wn + (lane & 15);
#pragma unroll
      for (int j = 0; j < 4; j++) {
        float p1 = acc1[i][j][r4];
        float p3 = acc3[i][j][r4];
        float h = (p1 / (1.f + __expf(-p1))) * p3 * w;
        dst[j * 16] = f2b(h);
      }
    }
  }
}

// ---------------- stage 2: Y = H @ W2, scatter atomicAdd into out ----------------
// wt2: bf16 [e][n=DIM][k=HID]; R2-proven 2-buffer structure.
__global__ __launch_bounds__(256) void stage2_kernel(
    const u16* __restrict__ hbuf, const u16* __restrict__ wt2,
    const int* __restrict__ elist, const int* __restrict__ count,
    float* __restrict__ out) {
  int wgid = blockIdx.x;
  int e = wgid & 7;
  int k = wgid >> 3;
  int tile = k & 63;
  int n0 = (k >> 6) * TN;          // 0..7
  int cnt = count[e];
  if (tile * TM >= cnt) return;

  __shared__ u16 As2[2][TM * BK];   // 2 x 8 KB
  __shared__ u16 Bs2[2][TN * BK];   // 2 x 8 KB
  __shared__ int slots[TM];

  int tid = threadIdx.x;
  if (tid < TM) {
    int r = tile * TM + tid;
    slots[tid] = (r < cnt) ? elist[e * NT + r] : -1;
  }
  __syncthreads();

  int lrow = tid >> 2;
  int lcol = (tid & 3) * 8;
  int sl0 = slots[lrow], sl1 = slots[lrow + 64];
  const u16* gA0 = hbuf + (size_t)(sl0 >= 0 ? sl0 : 0) * HID_ + lcol;
  const u16* gA1 = hbuf + (size_t)(sl1 >= 0 ? sl1 : 0) * HID_ + lcol;
  const u16* gBa = wt2 + ((size_t)e * DIM_ + n0 + lrow) * HID_ + lcol;
  const u16* gBb = gBa + (size_t)64 * HID_;

  int wv = tid >> 6, lane = tid & 63;
  int wm = (wv & 1) * 64, wn = (wv >> 1) * 64;
  int fr = lane & 15, fk = (lane >> 4) * 8;

  f32x4 acc[4][4];
  f32x4 zero = {0.f, 0.f, 0.f, 0.f};
#pragma unroll
  for (int i = 0; i < 4; i++)
#pragma unroll
    for (int j = 0; j < 4; j++) acc[i][j] = zero;

#define S2_STAGE(B, K0)                          \
  gl16(gA0 + (K0), &As2[B][tid * 8]);            \
  gl16(gA1 + (K0), &As2[B][2048 + tid * 8]);     \
  gl16(gBa + (K0), &Bs2[B][tid * 8]);            \
  gl16(gBb + (K0), &Bs2[B][2048 + tid * 8]);

#define S2_COMPUTE(B)                                                          \
  { bf16x8 afr[4], bfr[4];                                                     \
    _Pragma("unroll") for (int i = 0; i < 4; i++)                              \
      afr[i] = *(const bf16x8*)&As2[B][(wm + i * 16 + fr) * BK + fk];          \
    _Pragma("unroll") for (int j = 0; j < 4; j++)                              \
      bfr[j] = *(const bf16x8*)&Bs2[B][(wn + j * 16 + fr) * BK + fk];          \
    _Pragma("unroll") for (int i = 0; i < 4; i++)                              \
      _Pragma("unroll") for (int j = 0; j < 4; j++)                            \
        acc[i][j] = __builtin_amdgcn_mfma_f32_16x16x32_bf16(afr[i], bfr[j], acc[i][j], 0, 0, 0); }

  S2_STAGE(0, 0);
  __syncthreads();
  for (int k0 = 0; k0 < HID_; k0 += 2 * BK) {
    S2_STAGE(1, k0 + BK);
    S2_COMPUTE(0);
    __syncthreads();
    if (k0 + 2 * BK < HID_) { S2_STAGE(0, k0 + 2 * BK); }
    S2_COMPUTE(1);
    __syncthreads();
  }

#pragma unroll
  for (int i = 0; i < 4; i++) {
#pragma unroll
    for (int r4 = 0; r4 < 4; r4++) {
      int row = wm + i * 16 + (lane >> 4) * 4 + r4;
      int s = slots[row];
      if (s < 0) continue;
      int tk = s >> 1;
      float* dst = out + (size_t)tk * DIM_ + n0 + wn + (lane & 15);
#pragma unroll
      for (int j = 0; j < 4; j++) atomicAdd(&dst[j * 16], acc[i][j][r4]);
    }
  }
}

extern "C" void kernel_launch(void* const* d_in, const int* in_sizes, int n_in,
                              void* d_out, int out_size, void* d_ws, size_t ws_size,
                              hipStream_t stream) {
  const float* x = (const float*)d_in[0];
  const float* gw = (const float*)d_in[1];
  const float* w1 = (const float*)d_in[2];
  const float* w2 = (const float*)d_in[3];
  const float* w3 = (const float*)d_in[4];
  float* out = (float*)d_out;

  // workspace layout
  char* ws = (char*)d_ws;
  int* count = (int*)ws;                                    // 8 ints
  float* usage = (float*)(ws + 32);                         // 8 floats
  int* elist = (int*)(ws + 256);                            // NE*NT ints = 262144 B
  float* pw = (float*)(ws + 256 + 262144);                  // 2*NT floats = 65536 B
  u16* xb = (u16*)(ws + 327936);                            // NT*DIM bf16 = 16 MB
  u16* hbuf = (u16*)(ws + 327936 + 16777216);               // 2*NT*HID bf16 = 128 MB
  char* wbase = ws + 327936 + 16777216 + 134217728;         // 128 MB region
  u16* wt1 = (u16*)wbase;                                   // 64 MB
  u16* wt3 = (u16*)(wbase + 67108864);                      // 64 MB
  u16* wt2 = (u16*)wbase;                                   // aliases wt1 (used after stage1)

  hipMemsetAsync(d_out, 0, (size_t)(NT * DIM_ + 1) * sizeof(float), stream);
  hipMemsetAsync(ws, 0, 64, stream);

  cvt_x_kernel<<<(NT * DIM_) / (256 * 4), 256, 0, stream>>>(x, xb);
  router_kernel<<<128, 256, 0, stream>>>(x, gw, elist, pw, count, usage);
  aux_kernel<<<1, 64, 0, stream>>>(usage, out + (size_t)NT * DIM_);
  // transpose+convert w1, w3: fp32 [e][1024][4096] -> bf16 [e][4096][1024]
  tpose_kernel<<<dim3(HID_ / 64, DIM_ / 64, NE), 256, 0, stream>>>(w1, wt1, DIM_, HID_);
  tpose_kernel<<<dim3(HID_ / 64, DIM_ / 64, NE), 256, 0, stream>>>(w3, wt3, DIM_, HID_);
  stage1_kernel<<<dim3(NE * 64 * (HID_ / TN1)), 512, 0, stream>>>(xb, wt1, wt3, elist, count, pw, hbuf);
  // transpose+convert w2: fp32 [e][4096][1024] -> bf16 [e][1024][4096] (overwrites wt1 region)
  tpose_kernel<<<dim3(DIM_ / 64, HID_ / 64, NE), 256, 0, stream>>>(w2, wt2, HID_, DIM_);
  stage2_kernel<<<dim3(NE * 64 * (DIM_ / TN)), 256, 0, stream>>>(hbuf, wt2, elist, count, out);
}